// Round 7
// baseline (245.604 us; speedup 1.0000x reference)
//
#include <hip/hip_runtime.h>

#define D_MAX 2048
#define EPSF 1e-6f
#define E5F 148.4131591f   // e^5
#define BLK 512
#define GRID 1024
#define PBLK 256
#define PGRID 2048

// LDS per-date u64 layout (low->high):  stp:24 @2^4 | pden:24 @2^10 | n0:8 | n1:8
// Global per-date u64 layout (low->high): n0:12 | n1:12 | pden:18 @2^4 | stp:22 @2^1
// R12: CALIBRATION ROUND. R5-R11 falsified: block specialization, flush atomics,
// DS-atomic wall, per-thread MLP (ISA-forced depth-12 pipeline changed nothing; and
// Little's law at 32 waves/CU predicts >>6 TB/s even load-serialized). All kernels
// move 1-3.3 TB/s with nothing saturated. Two survivors: T-structure (our access
// shape throttles the CU memory path) vs T-floor (ANY streamer at this size runs
// ~1-3 TB/s here). probek = textbook m13-shape single-stream float4 read-sum over
// the same 201 MB, run before initk, block sums written into the g_pd region
// (initk re-zeroes it). Readout pre-committed: probe fast (absent from top-5,
// dtotal ~ +35us) => T-structure, restructure next; probe slow (in top-5 >=70us)
// => T-floor => we are at the demonstrated ceiling. Production = R11 unchanged.

typedef float f4 __attribute__((ext_vector_type(4)));
typedef int   i4 __attribute__((ext_vector_type(4)));

// Raw 16B global load, no wait: issue and move on.
#define GL4(dst, p) asm volatile("global_load_dwordx4 %0, %1, off" \
                                 : "=v"(dst) : "v"((const void*)(p)))

#define WAITBANK6(pv, tv, la, da, ga, gb)                        \
    asm volatile("s_waitcnt vmcnt(6)"                            \
                 : "+v"(pv), "+v"(tv), "+v"(la), "+v"(da), "+v"(ga), "+v"(gb))
#define WAITBANK0(pv, tv, la, da, ga, gb)                        \
    asm volatile("s_waitcnt vmcnt(0)"                            \
                 : "+v"(pv), "+v"(tv), "+v"(la), "+v"(da), "+v"(ga), "+v"(gb))

#define ISSUE6(pv, tv, la, da, ga, gb, i)   \
    do { int _i = (i);                      \
        GL4(pv, vp4 + _i);                  \
        GL4(tv, vt4 + _i);                  \
        GL4(la, lab4 + _i);                 \
        GL4(da, dt4 + _i);                  \
        GL4(ga, lg4 + 2 * _i);              \
        GL4(gb, lg4 + 2 * _i + 1);          \
    } while (0)

// ---------------- probek: textbook single-stream float4 read-sum ----------------
// One array at a time (sequential streams), trivial VALU, zero LDS beyond the
// 4-word reduce buffer, 2048x256 grid-stride. Writes per-block sums to scratch.
__global__ __launch_bounds__(PBLK)
void probek(const float4* __restrict__ a0, int n0,
            const float4* __restrict__ a1, int n1,
            const float4* __restrict__ a2, int n2,
            const float4* __restrict__ a3, int n3,
            const float4* __restrict__ a4, int n4,
            float* __restrict__ scratch) {
    __shared__ float s_s[PBLK / 64];
    const int NT = PGRID * PBLK;
    int g = blockIdx.x * PBLK + threadIdx.x;
    float4 acc = {0.f, 0.f, 0.f, 0.f};
    for (int i = g; i < n0; i += NT) { float4 v = a0[i]; acc.x += v.x; acc.y += v.y; acc.z += v.z; acc.w += v.w; }
    for (int i = g; i < n1; i += NT) { float4 v = a1[i]; acc.x += v.x; acc.y += v.y; acc.z += v.z; acc.w += v.w; }
    for (int i = g; i < n2; i += NT) { float4 v = a2[i]; acc.x += v.x; acc.y += v.y; acc.z += v.z; acc.w += v.w; }
    for (int i = g; i < n3; i += NT) { float4 v = a3[i]; acc.x += v.x; acc.y += v.y; acc.z += v.z; acc.w += v.w; }
    for (int i = g; i < n4; i += NT) { float4 v = a4[i]; acc.x += v.x; acc.y += v.y; acc.z += v.z; acc.w += v.w; }
    float s = acc.x + acc.y + acc.z + acc.w;
    for (int o = 32; o > 0; o >>= 1) s += __shfl_down(s, o);
    int lane = threadIdx.x & 63, wv = threadIdx.x >> 6;
    if (lane == 0) s_s[wv] = s;
    __syncthreads();
    if (threadIdx.x == 0) {
        float t = 0.f;
        for (int w = 0; w < PBLK / 64; w++) t += s_s[w];
        scratch[blockIdx.x] = t;   // keeps all loads live; region re-zeroed by initk
    }
}

__global__ void initk(unsigned long long* g_pd, double* sum_q, unsigned* n_valid,
                      const int* ndp) {
    int i = blockIdx.x * blockDim.x + threadIdx.x;
    int nd = ndp[0]; if (nd > D_MAX) nd = D_MAX;
    if (i == 0) { *sum_q = 0.0; *n_valid = 0u; }
    if (i < nd) g_pd[i] = 0ULL;
}

__device__ __forceinline__ void volElem(float p, float tg, double& accq, unsigned& accn) {
    if (tg > EPSF && p > EPSF) {   // NaN tgt fails compare, matching ~isnan & >eps
        float pv = fmaxf(p * p, EPSF);
        float tv = fmaxf(tg * tg, EPSF);
        accq += (double)(__fdividef(tv, pv) + __logf(pv));
        accn++;
    }
}

__device__ __forceinline__ void dirElem(int lb, int d, float l0, float l1,
                                        unsigned long long* s_pack) {
    if (lb >= 0) {
        // p1 = softmax(logits)[:,1]; segment-max shift cancels exactly in the ratios
        float p1 = __fdividef(1.0f, 1.0f + __expf(l0 - l1));
        float pe = __expf(p1);                 // in (1, e): no overflow
        float w  = (lb >= 1) ? E5F * p1 : p1;  // te * p1, te in {1, e^5}
        unsigned stp_i = (unsigned)(w * 16.0f + 0.5f);
        unsigned pd_i  = (unsigned)(pe * 1024.0f + 0.5f);
        unsigned long long inc = (unsigned long long)stp_i
                               | ((unsigned long long)pd_i << 24)
                               | (1ULL << (48 + 8 * (lb >= 1)));
        atomicAdd(&s_pack[d], inc);
    }
}

__device__ __forceinline__ void consume6(const f4& pv, const f4& tv,
                                         const i4& la, const i4& da,
                                         const f4& ga, const f4& gb,
                                         double& accq, unsigned& accn,
                                         unsigned long long* s_pack) {
    volElem(pv.x, tv.x, accq, accn);
    volElem(pv.y, tv.y, accq, accn);
    volElem(pv.z, tv.z, accq, accn);
    volElem(pv.w, tv.w, accq, accn);
    dirElem(la.x, da.x, ga.x, ga.y, s_pack);
    dirElem(la.y, da.y, ga.z, ga.w, s_pack);
    dirElem(la.z, da.z, gb.x, gb.y, s_pack);
    dirElem(la.w, da.w, gb.z, gb.w, s_pack);
}

__global__ __launch_bounds__(BLK, 6)   // VGPR cap ~85; 3 blocks/CU = 24 waves/CU
void fusedk(const f4* __restrict__ lg4, const i4* __restrict__ lab4,
            const f4* __restrict__ vp4, const f4* __restrict__ vt4,
            const i4* __restrict__ dt4, int B,
            unsigned long long* __restrict__ g_pd,
            double* __restrict__ sum_q, unsigned* __restrict__ n_valid,
            const int* __restrict__ ndp) {
    __shared__ unsigned long long s_pack[D_MAX];
    __shared__ double s_q[BLK / 64];
    __shared__ unsigned s_n[BLK / 64];
    int nd = ndp[0]; if (nd > D_MAX) nd = D_MAX;
    int B4 = B >> 2;

    for (int d = threadIdx.x; d < nd; d += BLK) s_pack[d] = 0ULL;
    __syncthreads();

    const int stride = GRID * BLK;
    int tid = blockIdx.x * BLK + threadIdx.x;
    double accq = 0.0;
    unsigned accn = 0u;

    int n = B4 / stride;       // = 4 at B = 8.4M
    int npair = n & ~1;        // pipeline handles an even number of rounds
    int kdone = 0;

    if (npair >= 2) {
        f4 pvA, tvA, gaA, gbA; i4 laA, daA;
        f4 pvB, tvB, gaB, gbB; i4 laB, daB;
        // prologue: 12 loads in flight
        ISSUE6(pvA, tvA, laA, daA, gaA, gbA, tid);
        ISSUE6(pvB, tvB, laB, daB, gaB, gbB, tid + stride);
        int k = 0;
        for (; k + 2 < npair; k += 2) {
            WAITBANK6(pvA, tvA, laA, daA, gaA, gbA);   // oldest 6 (bank A) done
            consume6(pvA, tvA, laA, daA, gaA, gbA, accq, accn, s_pack);
            ISSUE6(pvA, tvA, laA, daA, gaA, gbA, tid + (k + 2) * stride);
            WAITBANK6(pvB, tvB, laB, daB, gaB, gbB);
            consume6(pvB, tvB, laB, daB, gaB, gbB, accq, accn, s_pack);
            ISSUE6(pvB, tvB, laB, daB, gaB, gbB, tid + (k + 3) * stride);
        }
        WAITBANK6(pvA, tvA, laA, daA, gaA, gbA);       // B's 6 still outstanding
        consume6(pvA, tvA, laA, daA, gaA, gbA, accq, accn, s_pack);
        WAITBANK0(pvB, tvB, laB, daB, gaB, gbB);       // drain
        consume6(pvB, tvB, laB, daB, gaB, gbB, accq, accn, s_pack);
        kdone = npair;
    }
    // leftover rounds (n odd and/or B4 % stride) via plain compiler-scheduled loads
    for (int i = tid + kdone * stride; i < B4; i += stride) {
        f4 pv = vp4[i], tv = vt4[i];
        i4 la = lab4[i], da = dt4[i];
        f4 ga = lg4[2 * i], gb = lg4[2 * i + 1];
        consume6(pv, tv, la, da, ga, gb, accq, accn, s_pack);
    }
    // scalar tail (B % 4)
    int rem = B & 3;
    if (tid < rem) {
        int j = (B4 << 2) + tid;
        volElem(((const float*)vp4)[j], ((const float*)vt4)[j], accq, accn);
        dirElem(((const int*)lab4)[j], ((const int*)dt4)[j],
                ((const float*)lg4)[2 * j], ((const float*)lg4)[2 * j + 1], s_pack);
    }

    // ---- vol reduce: wave shuffle -> LDS across waves -> one atomic pair/block ----
    for (int o = 32; o > 0; o >>= 1) {
        accq += __shfl_down(accq, o);
        accn += __shfl_down(accn, o);
    }
    int lane = threadIdx.x & 63, wv = threadIdx.x >> 6;
    if (lane == 0) { s_q[wv] = accq; s_n[wv] = accn; }
    __syncthreads();   // also drains all s_pack LDS atomics before the flush below
    if (threadIdx.x == 0) {
        double q = 0.0; unsigned nn = 0u;
        for (int w = 0; w < BLK / 64; w++) { q += s_q[w]; nn += s_n[w]; }
        atomicAdd(sum_q, q);
        atomicAdd(n_valid, nn);
    }

    // ---- dir flush: ONE packed u64 global atomic per nonzero date, staggered ----
    int start = (blockIdx.x & 7) * BLK;
    if (start >= nd) start %= nd;
    for (int kk = 0; kk < (nd + BLK - 1) / BLK; kk++) {
        int d0 = threadIdx.x + kk * BLK;
        if (d0 < nd) {
            int d = d0 + start;
            if (d >= nd) d -= nd;
            unsigned long long c = s_pack[d];
            if (c) {
                unsigned stp24 = (unsigned)(c & 0xFFFFFFu);          // @2^4
                unsigned pd24  = (unsigned)((c >> 24) & 0xFFFFFFu);  // @2^10
                unsigned n0 = (unsigned)((c >> 48) & 0xFFu);
                unsigned n1 = (unsigned)(c >> 56);
                unsigned pd4  = (pd24 + 32u) >> 6;   // -> @2^4
                unsigned stp1 = (stp24 + 4u) >> 3;   // -> @2^1
                unsigned long long ginc = (unsigned long long)n0
                                        | ((unsigned long long)n1 << 12)
                                        | ((unsigned long long)pd4 << 24)
                                        | ((unsigned long long)stp1 << 42);
                atomicAdd(&g_pd[d], ginc);
            }
        }
    }
}

__global__ void finalk(const unsigned long long* __restrict__ g_pd, const int* __restrict__ ndp,
                       const double* __restrict__ sum_q, const unsigned* __restrict__ n_valid,
                       float* __restrict__ out) {
    __shared__ double s_ce[4];
    __shared__ unsigned s_c[4];
    int nd = ndp[0]; if (nd > D_MAX) nd = D_MAX;
    double ce = 0.0; unsigned cnt = 0u;
    for (int d = threadIdx.x; d < nd; d += 256) {
        unsigned long long pk = g_pd[d];
        unsigned n0 = (unsigned)(pk & 0xFFFu);
        unsigned n1 = (unsigned)((pk >> 12) & 0xFFFu);
        if (n0 + n1 >= 2u) {
            float pden = (float)((pk >> 24) & 0x3FFFFu) * (1.0f / 16.0f);
            float stp  = (float)(pk >> 42) * 0.5f;
            float td   = (float)n0 + (float)n1 * E5F;
            ce += (double)(__logf(fmaxf(pden, 1e-30f)) - stp / td);
            cnt++;
        }
    }
    for (int o = 32; o > 0; o >>= 1) { ce += __shfl_down(ce, o); cnt += __shfl_down(cnt, o); }
    int lane = threadIdx.x & 63, w = threadIdx.x >> 6;
    if (lane == 0) { s_ce[w] = ce; s_c[w] = cnt; }
    __syncthreads();
    if (threadIdx.x == 0) {
        double dce = s_ce[0] + s_ce[1] + s_ce[2] + s_ce[3];
        unsigned n = s_c[0] + s_c[1] + s_c[2] + s_c[3];
        unsigned nv = *n_valid;
        double vol = nv ? (*sum_q) / (double)nv : 0.0;
        double dir = dce / (double)(n ? n : 1u);
        out[0] = (float)(0.85 * vol + 0.15 * dir);
        out[1] = (float)vol;
        out[2] = (float)dir;
    }
}

extern "C" void kernel_launch(void* const* d_in, const int* in_sizes, int n_in,
                              void* d_out, int out_size, void* d_ws, size_t ws_size,
                              hipStream_t stream) {
    const f4* lg4 = (const f4*)d_in[0];
    const i4* lab4 = (const i4*)d_in[1];
    const f4* vp4 = (const f4*)d_in[2];
    const f4* vt4 = (const f4*)d_in[3];
    const i4* dt4 = (const i4*)d_in[4];
    const int* ndp = (const int*)d_in[5];
    int B = in_sizes[1];
    float* out = (float*)d_out;

    char* ws = (char*)d_ws;
    double*   sum_q   = (double*)(ws + 0);
    unsigned* n_valid = (unsigned*)(ws + 8);
    unsigned long long* g_pd = (unsigned long long*)(ws + 64);  // 16 KB

    // ---- calibration probe: runs BEFORE initk; writes into the g_pd region,
    // which initk then re-zeroes, so outputs are untouched. 2048 blocks x 4B = 8KB.
    probek<<<PGRID, PBLK, 0, stream>>>((const float4*)lg4, B / 2,
                                       (const float4*)lab4, B / 4,
                                       (const float4*)vp4, B / 4,
                                       (const float4*)vt4, B / 4,
                                       (const float4*)dt4, B / 4,
                                       (float*)g_pd);

    initk<<<(D_MAX + 255) / 256, 256, 0, stream>>>(g_pd, sum_q, n_valid, ndp);
    fusedk<<<GRID, BLK, 0, stream>>>(lg4, lab4, vp4, vt4, dt4, B,
                                     g_pd, sum_q, n_valid, ndp);
    finalk<<<1, 256, 0, stream>>>(g_pd, ndp, sum_q, n_valid, out);
}

// Round 8
// 239.015 us; speedup vs baseline: 1.0276x; 1.0276x over previous
//
#include <hip/hip_runtime.h>

#define D_MAX 2048
#define EPSF 1e-6f
#define E5F 148.4131591f   // e^5
#define BLK 256
#define GRID 2048          // probek geometry: 8 blocks/CU x 4 waves = 32 waves/CU

// LDS per-date u64 layout (low->high):  stp:24 @2^4 | pden:24 @2^10 | n0:8 | n1:8
// Global per-date u64 layout (low->high): n0:12 | n1:12 | pden:18 @2^4 | stp:22 @2^1
// R13: PROBEK-SHAPE PRODUCTION. R12's calibration: textbook plain-loop streamer
// (probek, 2048x256, no unroll/sched_barrier/asm, one stream per loop) moved the
// SAME 201MB at ~5.7 TB/s while production runs 2.7 -> T-structure confirmed,
// T-floor dead. Cross-tab of all kernels: every unroll+sched_barrier variant
// underperforms (megak 374us, volk 1.07 TB/s); plainest loops win (dirk 3.3,
// probek 5.7) -- my order-pinning was the poison (m141 in reverse). This round:
// production rebuilt in probek's exact shape. One kernel, two sequential PLAIN
// grid-stride loops: phase V (vp,vt -> QLIKE) then phase D (lab,dt,lg -> LDS
// histogram). No asm, no sched_barrier, no manual unroll, bare launch_bounds(256).
// Math byte-identical -> absmax 0.0. Predict fusedk 74 -> 45-55us, total ~180.
// If fusedk >= 70us: pairing/consume is the poison, not schedule -> next round
// ablates phase V with trivial consume.

__global__ void initk(unsigned long long* g_pd, double* sum_q, unsigned* n_valid,
                      const int* ndp) {
    int i = blockIdx.x * blockDim.x + threadIdx.x;
    int nd = ndp[0]; if (nd > D_MAX) nd = D_MAX;
    if (i == 0) { *sum_q = 0.0; *n_valid = 0u; }
    if (i < nd) g_pd[i] = 0ULL;
}

__device__ __forceinline__ void volElem(float p, float tg, double& accq, unsigned& accn) {
    if (tg > EPSF && p > EPSF) {   // NaN tgt fails compare, matching ~isnan & >eps
        float pv = fmaxf(p * p, EPSF);
        float tv = fmaxf(tg * tg, EPSF);
        accq += (double)(__fdividef(tv, pv) + __logf(pv));
        accn++;
    }
}

__device__ __forceinline__ void volGroup(const float4& p4, const float4& t4,
                                         double& accq, unsigned& accn) {
    volElem(p4.x, t4.x, accq, accn);
    volElem(p4.y, t4.y, accq, accn);
    volElem(p4.z, t4.z, accq, accn);
    volElem(p4.w, t4.w, accq, accn);
}

__device__ __forceinline__ void dirElem(int lb, int d, float l0, float l1,
                                        unsigned long long* s_pack) {
    if (lb >= 0) {
        // p1 = softmax(logits)[:,1]; segment-max shift cancels exactly in the ratios
        float p1 = __fdividef(1.0f, 1.0f + __expf(l0 - l1));
        float pe = __expf(p1);                 // in (1, e): no overflow
        float w  = (lb >= 1) ? E5F * p1 : p1;  // te * p1, te in {1, e^5}
        unsigned stp_i = (unsigned)(w * 16.0f + 0.5f);
        unsigned pd_i  = (unsigned)(pe * 1024.0f + 0.5f);
        unsigned long long inc = (unsigned long long)stp_i
                               | ((unsigned long long)pd_i << 24)
                               | (1ULL << (48 + 8 * (lb >= 1)));
        atomicAdd(&s_pack[d], inc);
    }
}

__device__ __forceinline__ void dirGroup(const int4& l4, const int4& d4,
                                         const float4& ga, const float4& gb,
                                         unsigned long long* s_pack) {
    dirElem(l4.x, d4.x, ga.x, ga.y, s_pack);
    dirElem(l4.y, d4.y, ga.z, ga.w, s_pack);
    dirElem(l4.z, d4.z, gb.x, gb.y, s_pack);
    dirElem(l4.w, d4.w, gb.z, gb.w, s_pack);
}

__global__ __launch_bounds__(BLK)   // probek-faithful: no min-waves clamp
void fusedk(const float4* __restrict__ lg4, const int4* __restrict__ lab4,
            const float4* __restrict__ vp4, const float4* __restrict__ vt4,
            const int4* __restrict__ dt4, int B,
            unsigned long long* __restrict__ g_pd,
            double* __restrict__ sum_q, unsigned* __restrict__ n_valid,
            const int* __restrict__ ndp) {
    __shared__ unsigned long long s_pack[D_MAX];
    __shared__ double s_q[BLK / 64];
    __shared__ unsigned s_n[BLK / 64];
    int nd = ndp[0]; if (nd > D_MAX) nd = D_MAX;
    int B4 = B >> 2;

    for (int d = threadIdx.x; d < nd; d += BLK) s_pack[d] = 0ULL;
    __syncthreads();

    const int NT = GRID * BLK;
    int g = blockIdx.x * BLK + threadIdx.x;

    // ---- phase V: plain grid-stride, 2 streams, no unroll/pinning ----
    double accq = 0.0;
    unsigned accn = 0u;
    for (int i = g; i < B4; i += NT) {
        float4 p = vp4[i], t = vt4[i];
        volGroup(p, t, accq, accn);
    }

    // ---- phase D: plain grid-stride, 4 streams, no unroll/pinning ----
    for (int i = g; i < B4; i += NT) {
        int4   la = lab4[i], da = dt4[i];
        float4 ga = lg4[2 * i], gb = lg4[2 * i + 1];
        dirGroup(la, da, ga, gb, s_pack);
    }

    // scalar tail (B % 4)
    int rem = B & 3;
    if (g < rem) {
        int j = (B4 << 2) + g;
        volElem(((const float*)vp4)[j], ((const float*)vt4)[j], accq, accn);
        dirElem(((const int*)lab4)[j], ((const int*)dt4)[j],
                ((const float*)lg4)[2 * j], ((const float*)lg4)[2 * j + 1], s_pack);
    }

    // ---- vol reduce: wave shuffle -> LDS across waves -> one atomic pair/block ----
    for (int o = 32; o > 0; o >>= 1) {
        accq += __shfl_down(accq, o);
        accn += __shfl_down(accn, o);
    }
    int lane = threadIdx.x & 63, wv = threadIdx.x >> 6;
    if (lane == 0) { s_q[wv] = accq; s_n[wv] = accn; }
    __syncthreads();   // also drains all s_pack LDS atomics before the flush below
    if (threadIdx.x == 0) {
        double q = 0.0; unsigned nn = 0u;
        for (int w = 0; w < BLK / 64; w++) { q += s_q[w]; nn += s_n[w]; }
        atomicAdd(sum_q, q);
        atomicAdd(n_valid, nn);
    }

    // ---- dir flush: ONE packed u64 global atomic per nonzero date, staggered ----
    int start = (blockIdx.x & 7) * BLK;
    if (start >= nd) start %= nd;
    for (int k = 0; k < (nd + BLK - 1) / BLK; k++) {
        int d0 = threadIdx.x + k * BLK;
        if (d0 < nd) {
            int d = d0 + start;
            if (d >= nd) d -= nd;
            unsigned long long c = s_pack[d];
            if (c) {
                unsigned stp24 = (unsigned)(c & 0xFFFFFFu);          // @2^4
                unsigned pd24  = (unsigned)((c >> 24) & 0xFFFFFFu);  // @2^10
                unsigned n0 = (unsigned)((c >> 48) & 0xFFu);
                unsigned n1 = (unsigned)(c >> 56);
                unsigned pd4  = (pd24 + 32u) >> 6;   // -> @2^4
                unsigned stp1 = (stp24 + 4u) >> 3;   // -> @2^1
                unsigned long long ginc = (unsigned long long)n0
                                        | ((unsigned long long)n1 << 12)
                                        | ((unsigned long long)pd4 << 24)
                                        | ((unsigned long long)stp1 << 42);
                atomicAdd(&g_pd[d], ginc);
            }
        }
    }
}

__global__ void finalk(const unsigned long long* __restrict__ g_pd, const int* __restrict__ ndp,
                       const double* __restrict__ sum_q, const unsigned* __restrict__ n_valid,
                       float* __restrict__ out) {
    __shared__ double s_ce[4];
    __shared__ unsigned s_c[4];
    int nd = ndp[0]; if (nd > D_MAX) nd = D_MAX;
    double ce = 0.0; unsigned cnt = 0u;
    for (int d = threadIdx.x; d < nd; d += 256) {
        unsigned long long pk = g_pd[d];
        unsigned n0 = (unsigned)(pk & 0xFFFu);
        unsigned n1 = (unsigned)((pk >> 12) & 0xFFFu);
        if (n0 + n1 >= 2u) {
            float pden = (float)((pk >> 24) & 0x3FFFFu) * (1.0f / 16.0f);
            float stp  = (float)(pk >> 42) * 0.5f;
            float td   = (float)n0 + (float)n1 * E5F;
            ce += (double)(__logf(fmaxf(pden, 1e-30f)) - stp / td);
            cnt++;
        }
    }
    for (int o = 32; o > 0; o >>= 1) { ce += __shfl_down(ce, o); cnt += __shfl_down(cnt, o); }
    int lane = threadIdx.x & 63, w = threadIdx.x >> 6;
    if (lane == 0) { s_ce[w] = ce; s_c[w] = cnt; }
    __syncthreads();
    if (threadIdx.x == 0) {
        double dce = s_ce[0] + s_ce[1] + s_ce[2] + s_ce[3];
        unsigned n = s_c[0] + s_c[1] + s_c[2] + s_c[3];
        unsigned nv = *n_valid;
        double vol = nv ? (*sum_q) / (double)nv : 0.0;
        double dir = dce / (double)(n ? n : 1u);
        out[0] = (float)(0.85 * vol + 0.15 * dir);
        out[1] = (float)vol;
        out[2] = (float)dir;
    }
}

extern "C" void kernel_launch(void* const* d_in, const int* in_sizes, int n_in,
                              void* d_out, int out_size, void* d_ws, size_t ws_size,
                              hipStream_t stream) {
    const float4* lg4 = (const float4*)d_in[0];
    const int4* lab4  = (const int4*)d_in[1];
    const float4* vp4 = (const float4*)d_in[2];
    const float4* vt4 = (const float4*)d_in[3];
    const int4* dt4   = (const int4*)d_in[4];
    const int* ndp    = (const int*)d_in[5];
    int B = in_sizes[1];
    float* out = (float*)d_out;

    char* ws = (char*)d_ws;
    double*   sum_q   = (double*)(ws + 0);
    unsigned* n_valid = (unsigned*)(ws + 8);
    unsigned long long* g_pd = (unsigned long long*)(ws + 64);  // 16 KB

    initk<<<(D_MAX + 255) / 256, 256, 0, stream>>>(g_pd, sum_q, n_valid, ndp);
    fusedk<<<GRID, BLK, 0, stream>>>(lg4, lab4, vp4, vt4, dt4, B,
                                     g_pd, sum_q, n_valid, ndp);
    finalk<<<1, 256, 0, stream>>>(g_pd, ndp, sum_q, n_valid, out);
}